// Round 1
// baseline (372.096 us; speedup 1.0000x reference)
//
#include <hip/hip_runtime.h>

// ---------------------------------------------------------------------------
// IDynamicDWConv pipeline, fp32 end-to-end.
// R9: conv3x3 de-LDS-bottlenecked. R8's conv64 wall (5.4us) == LDS-pipe
//     cycles: 8 waves/CU x (90cyc data + 108cyc weight-broadcast b128)/ci.
//     Fix: (a) weights via wave-uniform scalar loads (readfirstlane base ->
//     s_load through K$, zero LDS traffic); (b) tile 16x16, lane = 4px x 4oc,
//     CIB doubled (S=64: ks=4/CIB=16; S=32: ks=8/CIB=8) -> data LDS 432/ci/CU
//     < VALU 576/ci/SIMD -> VALU-bound at the 3.84us FMA floor.
//     Halved K-split also halves partial traffic: comb64 NP=4 (8.4MB read),
//     comb32 NP=8.
// dynconv / conv1x1 / avgpool / combs otherwise unchanged (R7/R8-verified).
// ---------------------------------------------------------------------------

__global__ __launch_bounds__(256) void avgpool4_k(const float* __restrict__ x,
                                                  float* __restrict__ y) {
    int idx = blockIdx.x * 256 + threadIdx.x;      // 524288
    int wo = idx & 63;
    int ho = (idx >> 6) & 63;
    int cz = idx >> 12;
    const float* base = x + ((long)cz * 256 + ho * 4) * 256 + wo * 4;
    float s = 0.f;
#pragma unroll
    for (int r = 0; r < 4; ++r) {
        float4 v = *(const float4*)(base + r * 256);
        s += v.x + v.y + v.z + v.w;
    }
    y[idx] = s * 0.0625f;
}

// K-split direct 3x3 conv (zero-pad SAME). Block: 256 thr = 4 waves; each
// wave = full 16x16 tile for a 4-oc slice; lane = 4 w-px x 4 oc.
// Weights fetched through the scalar path (wave-uniform address), so the
// LDS pipe only carries input-tile reads: 6 reads (3x(b128+b64)) per ci per
// lane vs 144 FMA -> VALU-bound.
// Partials out: [ks][n][oc][S][S].
template <int S, int CIB>
__global__ __launch_bounds__(256, 2) void conv3x3s_k(
    const float* __restrict__ in, const float* __restrict__ wgt,
    float* __restrict__ outp) {
    constexpr int KSN = 64 / CIB;
    constexpr int T = 16;
    constexpr int NT1 = S / T;
    constexpr int NT = NT1 * NT1;
    constexpr int HW = T + 2;                      // 18 cols used
    constexpr int SROW = 20;                       // padded row stride
    constexpr int TOT = CIB * 18 * HW;
    constexpr int NLD = (TOT + 255) / 256;
    constexpr int TAIL = TOT - (NLD - 1) * 256;
    __shared__ __align__(16) float s_in[CIB * 18 * SROW];

    const int tid = threadIdx.x;
    int z = blockIdx.x;
    const int ks = z % KSN; z /= KSN;
    const int ocg = z & 3; z >>= 2;
    const int tile = z % NT;
    const int n = z / NT;
    const int th0 = (tile / NT1) * T, tw0 = (tile % NT1) * T;
    const int oc0 = ocg * 16;

    // Input tile staging: flat coalesced burst, zero OOB.
    const float* inb = in + ((long)n * 64 + ks * CIB) * (S * S);
#pragma unroll
    for (int j = 0; j < NLD; ++j) {
        int idx = tid + j * 256;
        bool slot = (j < NLD - 1) || (tid < TAIL);
        int t = slot ? idx : 0;
        int ci = t / (18 * HW);
        int rem = t - ci * (18 * HW);
        int r = rem / HW;
        int c = rem - r * HW;
        int gh = th0 + r - 1, gw = tw0 + c - 1;
        float v = 0.f;
        if (slot && (unsigned)gh < (unsigned)S && (unsigned)gw < (unsigned)S)
            v = inb[ci * (S * S) + gh * S + gw];
        if (slot) s_in[ci * (18 * SROW) + r * SROW + c] = v;
    }
    __syncthreads();

    const int lane = tid & 63;
    const int wid = __builtin_amdgcn_readfirstlane(tid >> 6);  // 4-oc slice
    const int lx = lane & 3;                       // 4 strips across 16
    const int ly = lane >> 2;                      // 0..15 row
    const int px0 = lx * 4;

    // Wave-uniform weight base: [oc][ci][tap], oc stride 576.
    const float* wb = wgt + (long)(oc0 + wid * 4) * 576 + ks * (CIB * 9);

    float acc[4][4];
#pragma unroll
    for (int k = 0; k < 4; ++k)
#pragma unroll
        for (int p = 0; p < 4; ++p) acc[k][p] = 0.f;

#pragma unroll
    for (int ci = 0; ci < CIB; ++ci) {
        float xr[3][6];
#pragma unroll
        for (int r = 0; r < 3; ++r) {
            const float* rp = &s_in[ci * (18 * SROW) + (ly + r) * SROW + px0];
            float4 a = *(const float4*)rp;
            float2 b = *(const float2*)(rp + 4);
            xr[r][0] = a.x; xr[r][1] = a.y; xr[r][2] = a.z;
            xr[r][3] = a.w; xr[r][4] = b.x; xr[r][5] = b.y;
        }
#pragma unroll
        for (int k = 0; k < 4; ++k) {
            const float* wk = wb + k * 576 + ci * 9;
#pragma unroll
            for (int dh = 0; dh < 3; ++dh) {
                float w0 = wk[dh * 3 + 0];
                float w1 = wk[dh * 3 + 1];
                float w2 = wk[dh * 3 + 2];
#pragma unroll
                for (int p = 0; p < 4; ++p)
                    acc[k][p] += xr[dh][p] * w0 + xr[dh][p + 1] * w1 +
                                 xr[dh][p + 2] * w2;
            }
        }
    }

    const int gy = th0 + ly, gx = tw0 + px0;
    const long pstride = (long)2 * 64 * S * S;
    long off0 = ks * pstride +
                ((long)(n * 64 + oc0 + wid * 4)) * (S * S) + gy * S + gx;
#pragma unroll
    for (int k = 0; k < 4; ++k) {
        float4 v;
        v.x = acc[k][0]; v.y = acc[k][1]; v.z = acc[k][2]; v.w = acc[k][3];
        *(float4*)&outp[off0 + (long)k * (S * S)] = v;
    }
}

// Combine NP partials + bias (+lrelu / +res), float4 per thread.
template <int NP, int SSLOG, bool LRELU, bool RES>
__global__ __launch_bounds__(256) void comb_k(
    const float* __restrict__ P, const float* __restrict__ bias,
    const float* __restrict__ res, float* __restrict__ out) {
    const long pstride = (long)2 * 64 << SSLOG;
    long base = ((long)blockIdx.x * 256 + threadIdx.x) * 4;
    int c = (int)((base >> SSLOG) & 63);
    float4 v = *(const float4*)&P[base];
#pragma unroll
    for (int p = 1; p < NP; ++p) {
        float4 u = *(const float4*)&P[base + p * pstride];
        v.x += u.x; v.y += u.y; v.z += u.z; v.w += u.w;
    }
    float b = bias[c];
    v.x += b; v.y += b; v.z += b; v.w += b;
    if (LRELU) {
        v.x = v.x > 0.f ? v.x : 0.1f * v.x;
        v.y = v.y > 0.f ? v.y : 0.1f * v.y;
        v.z = v.z > 0.f ? v.z : 0.1f * v.z;
        v.w = v.w > 0.f ? v.w : 0.1f * v.w;
    }
    if (RES) {
        float4 r = *(const float4*)&res[base];
        v.x += r.x; v.y += r.y; v.z += r.z; v.w += r.w;
    }
    *(float4*)&out[base] = v;
}

// maxpool2 fused with final combine: y = sumNP(P) + bias + res, pool 2x2.
template <int NP>
__global__ __launch_bounds__(256) void maxpool_comb_k(
    const float* __restrict__ Pb, const float* __restrict__ bias,
    const float* __restrict__ res, float* __restrict__ P) {
    int idx = blockIdx.x * 256 + threadIdx.x;      // 131072
    int wo = idx & 31;
    int ho = (idx >> 5) & 31;
    int cz = idx >> 10;
    float bch = bias[cz & 63];
    float m = -3.4e38f;
#pragma unroll
    for (int dh = 0; dh < 2; ++dh)
#pragma unroll
        for (int dw = 0; dw < 2; ++dw) {
            long off = ((long)cz * 64 + ho * 2 + dh) * 64 + wo * 2 + dw;
            float y = bch + res[off];
#pragma unroll
            for (int p = 0; p < NP; ++p) y += Pb[off + (long)p * 524288];
            m = fmaxf(m, y);
        }
    P[idx] = m;
}

// 1x1 conv 64 -> 576 at 32x32. Block: 256 px, 8 oc. Weights in LDS.
__global__ __launch_bounds__(256) void conv1x1_k(
    const float* __restrict__ in, const float* __restrict__ w,
    const float* __restrict__ b, float* __restrict__ out) {
    __shared__ float s_in[32 * 256];
    __shared__ __align__(16) float s_w[64 * 8];
    const int tid = threadIdx.x;
    const int p0 = blockIdx.x * 256;
    const int cog = blockIdx.y;
    const int n = blockIdx.z;

    for (int idx = tid; idx < 512; idx += 256) {
        int j = idx >> 6;
        int ci = idx & 63;
        s_w[ci * 8 + j] = w[(long)cog * 512 + idx];
    }

    float acc[8];
#pragma unroll
    for (int i = 0; i < 8; ++i) acc[i] = b[cog * 8 + i];

    float pf[32];
#pragma unroll
    for (int i = 0; i < 32; ++i)
        pf[i] = in[(long)(n * 64 + i) * 1024 + p0 + tid];

    for (int chunk = 0; chunk < 64; chunk += 32) {
        __syncthreads();
#pragma unroll
        for (int i = 0; i < 32; ++i) s_in[i * 256 + tid] = pf[i];
        __syncthreads();
        if (chunk + 32 < 64) {
#pragma unroll
            for (int i = 0; i < 32; ++i)
                pf[i] = in[(long)(n * 64 + chunk + 32 + i) * 1024 + p0 + tid];
        }
#pragma unroll 4
        for (int ci = 0; ci < 32; ++ci) {
            float v = s_in[ci * 256 + tid];
            float4 w0 = *(const float4*)&s_w[(chunk + ci) * 8];
            float4 w1 = *(const float4*)&s_w[(chunk + ci) * 8 + 4];
            acc[0] += v * w0.x; acc[1] += v * w0.y;
            acc[2] += v * w0.z; acc[3] += v * w0.w;
            acc[4] += v * w1.x; acc[5] += v * w1.y;
            acc[6] += v * w1.z; acc[7] += v * w1.w;
        }
    }
#pragma unroll
    for (int oc = 0; oc < 8; ++oc)
        out[(long)(n * 576 + cog * 8 + oc) * 1024 + p0 + tid] = acc[oc];
}

// Fused bilinear x8 upsample + dynamic depthwise 3x3 (replicate pad on x).
// wt bilinear window staged in LDS: taps x 3 rows x 18 cols (block-uniform
// h0min=th/8-1, w0min=tw/8-1), clamp-duplicated so (j,j+1)/(r,r+1) always
// valid -> per tap 2 float2 LDS reads.
__global__ __launch_bounds__(256) void dynconv_k(
    const float* __restrict__ x, const float* __restrict__ wt,
    float* __restrict__ out) {
    __shared__ __align__(16) float s_x[10 * 132];
    __shared__ float s_wt[9 * 60];                 // [tap][3r][20c], 0..17 used
    const int tid = threadIdx.x;
    const int tx = tid & 31;
    const int ty = tid >> 5;
    const int tw = (blockIdx.x & 1) * 128;
    const int th = (blockIdx.x >> 1) * 8;
    const int cz = blockIdx.y;

    const float* xb = x + (long)cz * 65536;
    for (int idx = tid; idx < 1300; idx += 256) {
        int r = idx / 130;
        int c = idx - r * 130;
        int gh = min(max(th + r - 1, 0), 255);
        int gw = min(max(tw + c - 1, 0), 255);
        s_x[r * 132 + c] = xb[gh * 256 + gw];
    }

    const int h0min = th / 8 - 1;                  // th multiple of 8
    const int w0min = tw / 8 - 1;
    const float* wtb = wt + (long)cz * 9 * 1024;
    for (int i = tid; i < 540; i += 256) {
        int tap = i / 60;
        int rem = i - tap * 60;
        int r = rem / 20;
        int c = rem - r * 20;
        if (c < 18) {
            int gr = min(max(h0min + r, 0), 31);
            int gc = min(max(w0min + c, 0), 31);
            s_wt[i] = wtb[tap * 1024 + gr * 32 + gc];
        }
    }

    const int h = th + ty;
    const int wbase = tw + tx * 4;
    float src_h = h * 0.125f - 0.4375f;
    int h0 = (int)floorf(src_h);
    float fh = src_h - (float)h0;
    int r0 = h0 - h0min;                           // 0 or 1
    float src_w = wbase * 0.125f - 0.4375f;
    int w0 = (int)floorf(src_w);
    float fw0 = src_w - (float)w0;
    int j = w0 - w0min;                            // 0..16

    __syncthreads();

    float vals[3][6];
#pragma unroll
    for (int r = 0; r < 3; ++r) {
        const float* rp = &s_x[(ty + r) * 132 + tx * 4];
        float4 a = *(const float4*)rp;
        float2 b = *(const float2*)(rp + 4);
        vals[r][0] = a.x; vals[r][1] = a.y; vals[r][2] = a.z;
        vals[r][3] = a.w; vals[r][4] = b.x; vals[r][5] = b.y;
    }

    float acc[4] = {0.f, 0.f, 0.f, 0.f};
#pragma unroll
    for (int dh = 0; dh < 3; ++dh)
#pragma unroll
        for (int dw = 0; dw < 3; ++dw) {
            const float* p = &s_wt[(dh * 3 + dw) * 60 + r0 * 20 + j];
            float t0 = p[0], t1 = p[1];
            float b0 = p[20], b1 = p[21];
            float c0 = t0 + fh * (b0 - t0);
            float c1 = t1 + fh * (b1 - t1);
            float d = c1 - c0;
#pragma unroll
            for (int jj = 0; jj < 4; ++jj) {
                float wv = c0 + (fw0 + 0.125f * jj) * d;
                acc[jj] += vals[dh][jj + dw] * wv;
            }
        }

    float4 o;
    o.x = acc[0]; o.y = acc[1]; o.z = acc[2]; o.w = acc[3];
    *(float4*)&out[(long)cz * 65536 + h * 256 + wbase] = o;
}

extern "C" void kernel_launch(void* const* d_in, const int* in_sizes, int n_in,
                              void* d_out, int out_size, void* d_ws, size_t ws_size,
                              hipStream_t stream) {
    const float* x    = (const float*)d_in[0];
    const float* b1w1 = (const float*)d_in[1];
    const float* b1b1 = (const float*)d_in[2];
    const float* b1w2 = (const float*)d_in[3];
    const float* b1b2 = (const float*)d_in[4];
    const float* b2w1 = (const float*)d_in[5];
    const float* b2b1 = (const float*)d_in[6];
    const float* b2w2 = (const float*)d_in[7];
    const float* b2b2 = (const float*)d_in[8];
    const float* tokw = (const float*)d_in[9];
    const float* tokb = (const float*)d_in[10];
    float* out = (float*)d_out;
    float* ws = (float*)d_ws;

    // Buffers (floats):
    float* X0 = ws;                 // 524288 [2,64,64,64]
    float* X1 = ws + 524288;        // 524288
    float* T  = ws + 1048576;       // 524288
    float* P  = ws + 1572864;       // partials (4x524288 / 8x131072)
    float* Pm = ws + 5767168;       // 131072 [2,64,32,32]
    float* Q  = ws + 5898240;       // 131072
    float* U  = ws + 6029312;       // 131072
    float* WT = ws + 6160384;       // 1179648 [2,576,32,32]

    const int WSZ = 64 * 64 * 9;

    avgpool4_k<<<2048, 256, 0, stream>>>(x, X0);

    // ---- S=64 resblocks (conv: ks=4, CIB=16, tile 16x16, lane 4px x 4oc,
    //      scalar weights). grid = 4ks x 4ocg x 16tiles x 2n = 512.  ----
    conv3x3s_k<64, 16><<<512, 256, 0, stream>>>(X0, b1w1 + 0 * WSZ, P);
    comb_k<4, 12, true,  false><<<512, 256, 0, stream>>>(P, b1b1 + 0, nullptr, T);
    conv3x3s_k<64, 16><<<512, 256, 0, stream>>>(T, b1w2 + 0 * WSZ, P);
    comb_k<4, 12, false, true ><<<512, 256, 0, stream>>>(P, b1b2 + 0, X0, X1);

    conv3x3s_k<64, 16><<<512, 256, 0, stream>>>(X1, b1w1 + 1 * WSZ, P);
    comb_k<4, 12, true,  false><<<512, 256, 0, stream>>>(P, b1b1 + 64, nullptr, T);
    conv3x3s_k<64, 16><<<512, 256, 0, stream>>>(T, b1w2 + 1 * WSZ, P);
    comb_k<4, 12, false, true ><<<512, 256, 0, stream>>>(P, b1b2 + 64, X1, X0);

    conv3x3s_k<64, 16><<<512, 256, 0, stream>>>(X0, b1w1 + 2 * WSZ, P);
    comb_k<4, 12, true,  false><<<512, 256, 0, stream>>>(P, b1b1 + 128, nullptr, T);
    conv3x3s_k<64, 16><<<512, 256, 0, stream>>>(T, b1w2 + 2 * WSZ, P);
    maxpool_comb_k<4><<<512, 256, 0, stream>>>(P, b1b2 + 128, X0, Pm);

    // ---- S=32 resblocks (conv: ks=8, CIB=8, tile 16x16, lane 4px x 4oc,
    //      scalar weights). grid = 8ks x 4ocg x 4tiles x 2n = 256.  ----
    conv3x3s_k<32, 8><<<256, 256, 0, stream>>>(Pm, b2w1 + 0 * WSZ, P);
    comb_k<8, 10, true,  false><<<128, 256, 0, stream>>>(P, b2b1 + 0, nullptr, U);
    conv3x3s_k<32, 8><<<256, 256, 0, stream>>>(U, b2w2 + 0 * WSZ, P);
    comb_k<8, 10, false, true ><<<128, 256, 0, stream>>>(P, b2b2 + 0, Pm, Q);

    conv3x3s_k<32, 8><<<256, 256, 0, stream>>>(Q, b2w1 + 1 * WSZ, P);
    comb_k<8, 10, true,  false><<<128, 256, 0, stream>>>(P, b2b1 + 64, nullptr, U);
    conv3x3s_k<32, 8><<<256, 256, 0, stream>>>(U, b2w2 + 1 * WSZ, P);
    comb_k<8, 10, false, true ><<<128, 256, 0, stream>>>(P, b2b2 + 64, Q, Pm);

    conv3x3s_k<32, 8><<<256, 256, 0, stream>>>(Pm, b2w1 + 2 * WSZ, P);
    comb_k<8, 10, true,  false><<<128, 256, 0, stream>>>(P, b2b1 + 128, nullptr, U);
    conv3x3s_k<32, 8><<<256, 256, 0, stream>>>(U, b2w2 + 2 * WSZ, P);
    comb_k<8, 10, false, true ><<<128, 256, 0, stream>>>(P, b2b2 + 128, Pm, Q);

    conv1x1_k<<<dim3(4, 72, 2), 256, 0, stream>>>(Q, tokw, tokb, WT);

    dynconv_k<<<dim3(64, 128), 256, 0, stream>>>(x, WT, out);
}